// Round 3
// baseline (746.106 us; speedup 1.0000x reference)
//
#include <hip/hip_runtime.h>

constexpr int NTOK = 2048;
constexpr int CH   = 128;
constexpr int C4   = 32;
constexpr int NB   = 16;

typedef __attribute__((ext_vector_type(8))) __bf16 bf16x8;
typedef __attribute__((ext_vector_type(4))) float  f32x4;
typedef __attribute__((ext_vector_type(8))) unsigned short us8;

__device__ __forceinline__ unsigned short f2bf(float f) {
  union { float f; unsigned u; } v; v.f = f;
  unsigned r = v.u + 0x7fffu + ((v.u >> 16) & 1u);
  return (unsigned short)(r >> 16);
}
__device__ __forceinline__ float bf2f(unsigned short h) {
  union { unsigned u; float f; } v; v.u = ((unsigned)h) << 16;
  return v.f;
}

// rowsumH[b][c] = sum_n x_h[b][c][n]  (fp64, sync-free: 8 channels/block, 32 lanes each)
__global__ __launch_bounds__(256) void rs_kernel(const float* __restrict__ x_h,
                                                 double* __restrict__ rowsumH) {
  const int t = threadIdx.x;
  const int ch = t >> 5, lane = t & 31;
  const int c = blockIdx.x * 8 + ch;
  const int b = blockIdx.y;
  const float* rp = x_h + (size_t)(b * CH + c) * NTOK;
  double s = 0.0;
#pragma unroll
  for (int i = 0; i < 16; ++i) {
    float4 v = *(const float4*)(rp + (lane + 32 * i) * 4);
    s += (double)v.x + (double)v.y + (double)v.z + (double)v.w;
  }
  for (int off = 1; off <= 16; off <<= 1) s += __shfl_xor(s, off);
  if (lane == 0) rowsumH[b * CH + c] = s;
}

// P[b][c] = sum_d (sum_c' w_qk[d][c'] * rowsumH[b][c']) * w_qk[d][c]   (fp64)
__global__ __launch_bounds__(256) void p_kernel(const double* __restrict__ rowsumH,
                                                const float* __restrict__ w_qk,
                                                double* __restrict__ P) {
  const int t = threadIdx.x, b = blockIdx.x;
  __shared__ double Sl[C4];
  if (t < C4) {
    double s = 0.0;
    for (int c = 0; c < CH; ++c) s += (double)w_qk[t * CH + c] * rowsumH[b * CH + c];
    Sl[t] = s;
  }
  __syncthreads();
  if (t < CH) {
    double p = 0.0;
    for (int d = 0; d < C4; ++d) p += Sl[d] * (double)w_qk[d * CH + t];
    P[b * CH + t] = p;
  }
}

// q/k projection, VALU-floor: thread computes 4 consecutive n x 8 d.
// Outputs: bf16 hi/lo [B][N][32]; plus f32 copy for the x_o (k) side.
__global__ __launch_bounds__(256) void prep_qk(const float* __restrict__ x_h,
                                               const float* __restrict__ x_o,
                                               const float* __restrict__ w_qk,
                                               unsigned short* __restrict__ xhq_hi,
                                               unsigned short* __restrict__ xhq_lo,
                                               unsigned short* __restrict__ xokT_hi,
                                               unsigned short* __restrict__ xokT_lo,
                                               float* __restrict__ xokT_f32) {
  const int t = threadIdx.x;
  const int n0 = blockIdx.x * 256;
  const int b = blockIdx.y;
  const int which = blockIdx.z;
  const float* src = which ? x_o : x_h;
  unsigned short* dsth = which ? xokT_hi : xhq_hi;
  unsigned short* dstl = which ? xokT_lo : xhq_lo;

  __shared__ float Xt[32 * 256];   // 32 KB
  __shared__ float Wt[CH * 36];    // 18 KB, transposed w_qk [c][d]

  for (int i = 0; i < 4; ++i) {
    int flat4 = t + 256 * i;
    int d = flat4 >> 5, c4 = (flat4 & 31) * 4;
    float4 v = *(const float4*)(w_qk + d * CH + c4);
    Wt[(c4 + 0) * 36 + d] = v.x;
    Wt[(c4 + 1) * 36 + d] = v.y;
    Wt[(c4 + 2) * 36 + d] = v.z;
    Wt[(c4 + 3) * 36 + d] = v.w;
  }

  const int ng = t & 63;
  const int d0 = (t >> 6) * 8;    // wave-uniform
  float acc[4][8] = {};

  for (int cc = 0; cc < 4; ++cc) {
    __syncthreads();
    for (int i = 0; i < 8; ++i) {
      int flat4 = t + 256 * i;
      int row = flat4 >> 6, n4 = flat4 & 63;
      float4 v = *(const float4*)(src + (size_t)(b * CH + cc * 32 + row) * NTOK + n0 + n4 * 4);
      *(float4*)&Xt[row * 256 + n4 * 4] = v;
    }
    __syncthreads();
#pragma unroll 4
    for (int c64 = 0; c64 < 32; ++c64) {
      const int c = cc * 32 + c64;
      float4 x4 = *(const float4*)&Xt[c64 * 256 + ng * 4];
      float4 wa = *(const float4*)&Wt[c * 36 + d0];
      float4 wb = *(const float4*)&Wt[c * 36 + d0 + 4];
      acc[0][0] += x4.x * wa.x; acc[0][1] += x4.x * wa.y; acc[0][2] += x4.x * wa.z; acc[0][3] += x4.x * wa.w;
      acc[0][4] += x4.x * wb.x; acc[0][5] += x4.x * wb.y; acc[0][6] += x4.x * wb.z; acc[0][7] += x4.x * wb.w;
      acc[1][0] += x4.y * wa.x; acc[1][1] += x4.y * wa.y; acc[1][2] += x4.y * wa.z; acc[1][3] += x4.y * wa.w;
      acc[1][4] += x4.y * wb.x; acc[1][5] += x4.y * wb.y; acc[1][6] += x4.y * wb.z; acc[1][7] += x4.y * wb.w;
      acc[2][0] += x4.z * wa.x; acc[2][1] += x4.z * wa.y; acc[2][2] += x4.z * wa.z; acc[2][3] += x4.z * wa.w;
      acc[2][4] += x4.z * wb.x; acc[2][5] += x4.z * wb.y; acc[2][6] += x4.z * wb.z; acc[2][7] += x4.z * wb.w;
      acc[3][0] += x4.w * wa.x; acc[3][1] += x4.w * wa.y; acc[3][2] += x4.w * wa.z; acc[3][3] += x4.w * wa.w;
      acc[3][4] += x4.w * wb.x; acc[3][5] += x4.w * wb.y; acc[3][6] += x4.w * wb.z; acc[3][7] += x4.w * wb.w;
    }
  }

#pragma unroll
  for (int j = 0; j < 4; ++j) {
    const int n = n0 + ng * 4 + j;
    const size_t base = (size_t)(b * NTOK + n) * C4 + d0;
    us8 hv, lv;
#pragma unroll
    for (int k = 0; k < 8; ++k) {
      unsigned short h = f2bf(acc[j][k]);
      hv[k] = h;
      lv[k] = f2bf(acc[j][k] - bf2f(h));
    }
    *(us8*)(dsth + base) = hv;
    *(us8*)(dstl + base) = lv;
    if (which) {
      *(float4*)(xokT_f32 + base) = make_float4(acc[j][0], acc[j][1], acc[j][2], acc[j][3]);
      *(float4*)(xokT_f32 + base + 4) = make_float4(acc[j][4], acc[j][5], acc[j][6], acc[j][7]);
    }
  }
}

// inv[b][m] = 1/(1e-9 + sum_c P[b][c]*x_o[b][c][m])  (fp64 dot)
// S2[b][d] += sum_m xo_k[d][m]*inv[m]
__global__ __launch_bounds__(256) void inv_s2(const float* __restrict__ x_o,
                                              const double* __restrict__ P,
                                              const float* __restrict__ xokT_f32,
                                              float* __restrict__ inv,
                                              float* __restrict__ S2) {
  const int t = threadIdx.x;
  const int b = blockIdx.y;
  const int m = blockIdx.x * 256 + t;
  __shared__ double Pl[CH];
  __shared__ float S2l[C4];
  if (t < CH) Pl[t] = P[b * CH + t];
  if (t < C4) S2l[t] = 0.f;
  __syncthreads();
  double cs = 0.0;
  const float* xp = x_o + (size_t)b * CH * NTOK + m;
#pragma unroll 8
  for (int c = 0; c < CH; ++c) cs += Pl[c] * (double)xp[(size_t)c * NTOK];
  float iv = (float)(1.0 / (1e-9 + cs));
  inv[b * NTOK + m] = iv;
  const float* rp = xokT_f32 + (size_t)(b * NTOK + m) * C4;
  for (int dd = 0; dd < C4; ++dd) {
    int d2 = (dd + t) & 31;
    atomicAdd(&S2l[d2], rp[d2] * iv);
  }
  __syncthreads();
  if (t < C4) atomicAdd(&S2[b * C4 + t], S2l[t]);
}

// U[b][d][c'] += sum_m xo_k[d][m]*inv[m]*x_o[b][c'][m]
__global__ __launch_bounds__(256) void u_kernel(const float* __restrict__ x_o,
                                                const float* __restrict__ xokT_f32,
                                                const float* __restrict__ inv,
                                                float* __restrict__ U) {
  const int t = threadIdx.x;
  const int c0 = blockIdx.x * 8;
  const int mbase0 = blockIdx.y * 512;
  const int b = blockIdx.z;
  const int d = t & 31, cl = t >> 5;
  __shared__ float Xs[8][256];
  float acc = 0.f;
  for (int cc = 0; cc < 2; ++cc) {
    const int mb = mbase0 + cc * 256;
    __syncthreads();
    for (int i = 0; i < 2; ++i) {
      int flat = t + 256 * i;
      int row = flat >> 6, f4 = flat & 63;
      float4 xv = *(const float4*)(x_o + (size_t)(b * CH + c0 + row) * NTOK + mb + f4 * 4);
      float4 iv = *(const float4*)(inv + b * NTOK + mb + f4 * 4);
      xv.x *= iv.x; xv.y *= iv.y; xv.z *= iv.z; xv.w *= iv.w;
      *(float4*)&Xs[row][f4 * 4] = xv;
    }
    __syncthreads();
    const float* ap = xokT_f32 + (size_t)(b * NTOK + mb) * C4 + d;
#pragma unroll 4
    for (int mm = 0; mm < 256; mm += 4) {
      float4 xq = *(const float4*)&Xs[cl][mm];
      float a0 = ap[(mm + 0) * C4];
      float a1 = ap[(mm + 1) * C4];
      float a2 = ap[(mm + 2) * C4];
      float a3 = ap[(mm + 3) * C4];
      acc += a0 * xq.x + a1 * xq.y + a2 * xq.z + a3 * xq.w;
    }
  }
  atomicAdd(&U[(size_t)(b * C4 + d) * CH + c0 + cl], acc);
}

// T2[b][c][d] = sum_c' U[b][d][c']*w_v[c][c'] + S2[b][d]*b_v[c]   (c-major for xr)
__global__ __launch_bounds__(256) void t_kernel(const float* __restrict__ U,
                                                const float* __restrict__ w_v,
                                                const float* __restrict__ b_v,
                                                const float* __restrict__ S2,
                                                float* __restrict__ T2) {
  const int t = threadIdx.x, b = blockIdx.x;
  __shared__ float Wl[CH * CH];
  for (int i = 0; i < 16; ++i) {
    int flat = t + 256 * i;
    *(float4*)&Wl[flat * 4] = *(const float4*)(w_v + flat * 4);
  }
  __syncthreads();
  const int d = t & 31;
  const int cg = (t >> 5) * 16;
  float acc[16] = {};
  const float* up = U + (size_t)(b * C4 + d) * CH;
  for (int cp = 0; cp < CH; ++cp) {
    float u = up[cp];
#pragma unroll
    for (int j = 0; j < 16; ++j) acc[j] += u * Wl[(cg + j) * CH + cp];
  }
  float s2 = S2[b * C4 + d];
#pragma unroll
  for (int j = 0; j < 16; ++j) {
    acc[j] += s2 * b_v[cg + j];
    T2[(size_t)(b * CH + cg + j) * C4 + d] = acc[j];
  }
}

// out0[b][c][n] = sum_d q[b][n][d] * T2[b][c][d]; q = hi+lo reconstruction
__global__ __launch_bounds__(256) void xr_kernel(const unsigned short* __restrict__ xhq_hi,
                                                 const unsigned short* __restrict__ xhq_lo,
                                                 const float* __restrict__ T2,
                                                 float* __restrict__ out0) {
  const int t = threadIdx.x;
  const int n0 = blockIdx.x * 128;
  const int b = blockIdx.y;
  __shared__ float Tl[CH * 36];
  for (int i = 0; i < 4; ++i) {
    int flat4 = t + 256 * i;
    int c = flat4 >> 3, dg = (flat4 & 7) * 4;
    float4 v = *(const float4*)(T2 + (size_t)(b * CH + c) * C4 + dg);
    *(float4*)&Tl[c * 36 + dg] = v;
  }
  __syncthreads();

  const int na = n0 + (t & 63);
  const int nb2 = na + 64;
  const int cg = (t >> 6) * 32;

  float qa[C4], qb[C4];
#pragma unroll
  for (int i = 0; i < 4; ++i) {
    us8 h = *(const us8*)(xhq_hi + (size_t)(b * NTOK + na) * C4 + i * 8);
    us8 l = *(const us8*)(xhq_lo + (size_t)(b * NTOK + na) * C4 + i * 8);
#pragma unroll
    for (int j = 0; j < 8; ++j) qa[i * 8 + j] = bf2f(h[j]) + bf2f(l[j]);
    us8 h2 = *(const us8*)(xhq_hi + (size_t)(b * NTOK + nb2) * C4 + i * 8);
    us8 l2 = *(const us8*)(xhq_lo + (size_t)(b * NTOK + nb2) * C4 + i * 8);
#pragma unroll
    for (int j = 0; j < 8; ++j) qb[i * 8 + j] = bf2f(h2[j]) + bf2f(l2[j]);
  }

  float* op = out0 + (size_t)b * CH * NTOK;
  for (int c = cg; c < cg + 32; ++c) {
    float acc1 = 0.f, acc2 = 0.f;
#pragma unroll
    for (int dd = 0; dd < C4; dd += 4) {
      float4 tv = *(const float4*)&Tl[c * 36 + dd];
      acc1 += qa[dd] * tv.x + qa[dd + 1] * tv.y + qa[dd + 2] * tv.z + qa[dd + 3] * tv.w;
      acc2 += qb[dd] * tv.x + qb[dd + 1] * tv.y + qb[dd + 2] * tv.z + qb[dd + 3] * tv.w;
    }
    op[(size_t)c * NTOK + na] = acc1;
    op[(size_t)c * NTOK + nb2] = acc2;
  }
}

// attention[b][n][m] = (q[n,:].k[:,m]) * inv[m]; 64n x 256m per block;
// epilogue via LDS -> 16B nontemporal stores (ext-vector f32x4 operand)
__global__ __launch_bounds__(256) void attn_kernel(const unsigned short* __restrict__ xhq_hi,
                                                   const unsigned short* __restrict__ xhq_lo,
                                                   const unsigned short* __restrict__ xokT_hi,
                                                   const unsigned short* __restrict__ xokT_lo,
                                                   const float* __restrict__ inv,
                                                   float* __restrict__ out1) {
  const int t = threadIdx.x;
  const int wave = t >> 6, lane = t & 63;
  const int quad = lane >> 4, l16 = lane & 15;
  const int m00 = blockIdx.x * 256;
  const int n0 = blockIdx.y * 64;
  const int b = blockIdx.z;

  __shared__ float Cs[64 * 68];

  const int n = n0 + wave * 16 + l16;
  const size_t abase = (size_t)(b * NTOK + n) * C4 + quad * 8;
  const bf16x8 ah = *(const bf16x8*)(const void*)(xhq_hi + abase);
  const bf16x8 al = *(const bf16x8*)(const void*)(xhq_lo + abase);

  const int srow = t >> 2, scg = t & 3;

  for (int mt = 0; mt < 4; ++mt) {
    const int m0 = m00 + mt * 64;
    bf16x8 bh[4], bl[4];
    float invv[4];
#pragma unroll
    for (int tt = 0; tt < 4; ++tt) {
      int m = m0 + tt * 16 + l16;
      size_t bbase = (size_t)(b * NTOK + m) * C4 + quad * 8;
      bh[tt] = *(const bf16x8*)(const void*)(xokT_hi + bbase);
      bl[tt] = *(const bf16x8*)(const void*)(xokT_lo + bbase);
      invv[tt] = inv[b * NTOK + m];
    }
#pragma unroll
    for (int tt = 0; tt < 4; ++tt) {
      f32x4 z = {0.f, 0.f, 0.f, 0.f};
      f32x4 acc = __builtin_amdgcn_mfma_f32_16x16x32_bf16(al, bh[tt], z, 0, 0, 0);
      acc = __builtin_amdgcn_mfma_f32_16x16x32_bf16(ah, bl[tt], acc, 0, 0, 0);
      acc = __builtin_amdgcn_mfma_f32_16x16x32_bf16(ah, bh[tt], acc, 0, 0, 0);
#pragma unroll
      for (int r = 0; r < 4; ++r)
        Cs[(wave * 16 + quad * 4 + r) * 68 + tt * 16 + l16] = acc[r] * invv[tt];
    }
    __syncthreads();
#pragma unroll
    for (int k = 0; k < 4; ++k) {
      f32x4 v = *(const f32x4*)&Cs[srow * 68 + scg * 16 + k * 4];
      size_t off = ((size_t)(b * NTOK) + n0 + srow) * NTOK + m0 + scg * 16 + k * 4;
      __builtin_nontemporal_store(v, (f32x4*)(out1 + off));
    }
    __syncthreads();
  }
}

extern "C" void kernel_launch(void* const* d_in, const int* in_sizes, int n_in,
                              void* d_out, int out_size, void* d_ws, size_t ws_size,
                              hipStream_t stream) {
  (void)in_sizes; (void)n_in; (void)out_size; (void)ws_size;
  const float* x_h  = (const float*)d_in[0];
  const float* x_o  = (const float*)d_in[1];
  const float* w_qk = (const float*)d_in[2];
  const float* w_v  = (const float*)d_in[3];
  const float* b_v  = (const float*)d_in[4];
  float* out0 = (float*)d_out;
  float* out1 = out0 + (size_t)NB * CH * NTOK;

  char* ws = (char*)d_ws;
  unsigned short* xhq_hi  = (unsigned short*)(ws + 0);
  unsigned short* xhq_lo  = (unsigned short*)(ws + 2097152);
  unsigned short* xokT_hi = (unsigned short*)(ws + 4194304);
  unsigned short* xokT_lo = (unsigned short*)(ws + 6291456);
  float* xokT_f32 = (float*)(ws + 8388608);
  float* inv      = (float*)(ws + 12582912);
  float* S2       = (float*)(ws + 12713984);
  float* U        = (float*)(ws + 12716032);
  float* T2       = (float*)(ws + 12978176);
  double* rowsumH = (double*)(ws + 13240320);
  double* P       = (double*)(ws + 13256704);

  (void)hipMemsetAsync(S2, 0, 2048 + 262144, stream);

  rs_kernel <<<dim3(16, NB), 256, 0, stream>>>(x_h, rowsumH);
  p_kernel  <<<NB, 256, 0, stream>>>(rowsumH, w_qk, P);
  prep_qk   <<<dim3(8, NB, 2), 256, 0, stream>>>(x_h, x_o, w_qk, xhq_hi, xhq_lo,
                                                 xokT_hi, xokT_lo, xokT_f32);
  inv_s2    <<<dim3(8, NB), 256, 0, stream>>>(x_o, P, xokT_f32, inv, S2);
  u_kernel  <<<dim3(16, 4, NB), 256, 0, stream>>>(x_o, xokT_f32, inv, U);
  t_kernel  <<<NB, 256, 0, stream>>>(U, w_v, b_v, S2, T2);
  xr_kernel <<<dim3(16, NB), 256, 0, stream>>>(xhq_hi, xhq_lo, T2, out0);
  attn_kernel<<<dim3(8, 32, NB), 256, 0, stream>>>(xhq_hi, xhq_lo, xokT_hi, xokT_lo,
                                                   inv, out1);
}